// Round 4
// baseline (250.623 us; speedup 1.0000x reference)
//
#include <hip/hip_runtime.h>

// YOLO loss: preds/targets (N,7,7,30) fp32 -> scalar. 192.7 MB read.
// R3: (a) register-dbuf prefetch pipeline in a persistent one-wave-per-block
// kernel (overlap next slice's global loads with current compute);
// (b) diagnostic probe_read: 32 MB coalesced read bench appended to split
// "kernel-structure-bound" from "environment-bound" (R0-R2 all pinned at
// 75 us / 1.28 TB/s across wildly different structures).

#define SGRID 7
#define DDIM 30
#define NCLS 20
#define LAMBDA_NOOBJ 0.5f
#define IOU_EPS 1e-10f

#define SLICE_CELLS 64
#define SLICE_FLOATS (SLICE_CELLS * DDIM)  // 1920 floats = 7.68 KB
#define MAIN_BLOCKS 2560                   // one 64-lane wave per block

#define PROBE_BLOCKS 2048
#define PROBE_THREADS 256
#define PROBE_F4 (1 << 21)                 // 2M float4 = 32 MiB

// pv/tv point into LDS (per-cell, constant offsets -> ds_read_b32).
__device__ __forceinline__ float cell_loss(const float* pv, const float* tv) {
    float loss = 0.0f;
    float iou0 = 0.0f, iou1 = 0.0f;
#pragma unroll
    for (int b = 0; b < 2; ++b) {
        const float x1 = pv[b * 5 + 0], y1 = pv[b * 5 + 1];
        const float w1 = pv[b * 5 + 2], h1 = pv[b * 5 + 3];
        const float x2 = tv[b * 5 + 0], y2 = tv[b * 5 + 1];
        const float w2 = tv[b * 5 + 2], h2 = tv[b * 5 + 3];
        float iw = fminf(x1 + 0.5f * w1, x2 + 0.5f * w2) -
                   fmaxf(x1 - 0.5f * w1, x2 - 0.5f * w2);
        iw = fmaxf(iw, 0.0f);
        float ih = fminf(y1 + 0.5f * h1, y2 + 0.5f * h2) -
                   fmaxf(y1 - 0.5f * h1, y2 - 0.5f * h2);
        ih = fmaxf(ih, 0.0f);
        const float inter = iw * ih;
        const float uni = w1 * h1 + w2 * h2 - inter;
        const float iou = inter / (uni + IOU_EPS);
        if (b == 0) iou0 = iou; else iou1 = iou;
    }
    const bool sel1 = iou1 > iou0;  // argmax ties -> box 0

    {   // coord loss, gated by has_obj = targets[...,4] > 0
        const float px = sel1 ? pv[5] : pv[0];
        const float py = sel1 ? pv[6] : pv[1];
        const float tx = sel1 ? tv[5] : tv[0];
        const float ty = sel1 ? tv[6] : tv[1];
        const float dx = px - tx, dy = py - ty;
        if (tv[4] > 0.0f) loss += dx * dx + dy * dy;
    }

    // class SSE + running argmax of target class (ties -> first),
    // tracking pred-at-gt-class by value.
    float gt_val = tv[10];
    float pc_gt = pv[10];
#pragma unroll
    for (int j = 0; j < NCLS; ++j) {
        const float pc = pv[10 + j], tc = tv[10 + j];
        const float d = pc - tc;
        loss += d * d;
        const bool gm = tc > gt_val;
        gt_val = gm ? tc : gt_val;
        pc_gt = gm ? pc : pc_gt;
    }

    // conf loss: w_b * iou_b^2 * (pc_gt - 1)^2
    const float c = pc_gt - 1.0f;
    const float d0 = iou0 * c, d1 = iou1 * c;
    const float w0 = sel1 ? LAMBDA_NOOBJ : 1.0f;
    const float w1 = sel1 ? 1.0f : LAMBDA_NOOBJ;
    loss += w0 * d0 * d0 + w1 * d1 * d1;
    return loss;
}

__device__ __forceinline__ void load_slice(const float* __restrict__ g, int lane,
                                           float4 (&r)[7], float2& r2) {
    const float4* g4 = (const float4*)g;
#pragma unroll
    for (int k = 0; k < 7; ++k) r[k] = g4[lane + (k << 6)];
    r2 = ((const float2*)g)[896 + lane];
}

__device__ __forceinline__ void store_slice(float* l, int lane,
                                            const float4 (&r)[7], const float2& r2) {
#pragma unroll
    for (int k = 0; k < 7; ++k) ((float4*)l)[lane + (k << 6)] = r[k];
    ((float2*)l)[896 + lane] = r2;
}

__global__ __launch_bounds__(64) void yolo_loss_main(
    const float* __restrict__ preds, const float* __restrict__ targets,
    float* __restrict__ partials, int n_cells) {
    __shared__ float lp[SLICE_FLOATS];  // one wave per block: wave-private
    __shared__ float lt[SLICE_FLOATS];

    const int lane = threadIdx.x;
    const int nwaves = gridDim.x;
    const int n_slices = n_cells / SLICE_CELLS;

    float loss = 0.0f;
    int s = blockIdx.x;

    float4 ap[7], at[7]; float2 ap2, at2;
    float4 bp[7], bt[7]; float2 bp2, bt2;

    if (s < n_slices) {
        load_slice(preds + (size_t)s * SLICE_FLOATS, lane, ap, ap2);
        load_slice(targets + (size_t)s * SLICE_FLOATS, lane, at, at2);
    }
    while (s < n_slices) {
        // ---- phase A: write A-regs to LDS, prefetch next into B-regs,
        // consume from LDS (prefetch vmcnt overlaps consume's compute).
        store_slice(lp, lane, ap, ap2);
        store_slice(lt, lane, at, at2);
        {
            const int s2 = s + nwaves;
            if (s2 < n_slices) {
                load_slice(preds + (size_t)s2 * SLICE_FLOATS, lane, bp, bp2);
                load_slice(targets + (size_t)s2 * SLICE_FLOATS, lane, bt, bt2);
            }
            loss += cell_loss(lp + lane * DDIM, lt + lane * DDIM);
            s = s2;
        }
        if (s >= n_slices) break;
        // ---- phase B: mirror (DS ops are per-wave in-order: the phase-A
        // reads complete before these writes land; wave-private -> no barrier)
        store_slice(lp, lane, bp, bp2);
        store_slice(lt, lane, bt, bt2);
        {
            const int s2 = s + nwaves;
            if (s2 < n_slices) {
                load_slice(preds + (size_t)s2 * SLICE_FLOATS, lane, ap, ap2);
                load_slice(targets + (size_t)s2 * SLICE_FLOATS, lane, at, at2);
            }
            loss += cell_loss(lp + lane * DDIM, lt + lane * DDIM);
            s = s2;
        }
    }

    // Tail cells (dead for this shape: 802816 = 64*12544).
    const int tail0 = n_slices * SLICE_CELLS;
    if (blockIdx.x == 0 && tail0 + lane < n_cells) {
        float pv[DDIM], tv[DDIM];
        const float* gp = preds + (size_t)(tail0 + lane) * DDIM;
        const float* gt = targets + (size_t)(tail0 + lane) * DDIM;
#pragma unroll
        for (int i = 0; i < DDIM; ++i) { pv[i] = gp[i]; tv[i] = gt[i]; }
        loss += cell_loss(pv, tv);
    }

#pragma unroll
    for (int off = 32; off > 0; off >>= 1) loss += __shfl_down(loss, off, 64);
    if (lane == 0) partials[blockIdx.x] = loss;
}

#define RTHREADS 1024
__global__ __launch_bounds__(RTHREADS) void yolo_loss_reduce(
    const float* __restrict__ partials, int n, float inv_n,
    float* __restrict__ out) {
    __shared__ float red[RTHREADS / 64];
    float v = 0.0f;
    for (int i = threadIdx.x; i < n; i += RTHREADS) v += partials[i];
#pragma unroll
    for (int off = 32; off > 0; off >>= 1) v += __shfl_down(v, off, 64);
    if ((threadIdx.x & 63) == 0) red[threadIdx.x >> 6] = v;
    __syncthreads();
    if (threadIdx.x == 0) {
        float s = 0.0f;
#pragma unroll
        for (int w = 0; w < RTHREADS / 64; ++w) s += red[w];
        out[0] = s * inv_n;
    }
}

// Diagnostic: pure coalesced 32 MiB read-reduce, mirrors the 6.29 TB/s
// float4-copy microbench structure. Sinks to d_ws (never touches d_out).
__global__ __launch_bounds__(PROBE_THREADS) void probe_read(
    const float4* __restrict__ src, float* __restrict__ sink) {
    const int tid = blockIdx.x * PROBE_THREADS + threadIdx.x;
    const int stride = PROBE_BLOCKS * PROBE_THREADS;  // 524288
    const float4 a = src[tid];
    const float4 b = src[tid + stride];
    const float4 c = src[tid + 2 * stride];
    const float4 d = src[tid + 3 * stride];
    float v = (a.x + a.y + a.z + a.w) + (b.x + b.y + b.z + b.w) +
              (c.x + c.y + c.z + c.w) + (d.x + d.y + d.z + d.w);
#pragma unroll
    for (int off = 32; off > 0; off >>= 1) v += __shfl_down(v, off, 64);
    __shared__ float red[PROBE_THREADS / 64];
    if ((threadIdx.x & 63) == 0) red[threadIdx.x >> 6] = v;
    __syncthreads();
    if (threadIdx.x == 0) {
        float ssum = 0.0f;
#pragma unroll
        for (int w = 0; w < PROBE_THREADS / 64; ++w) ssum += red[w];
        sink[blockIdx.x] = ssum;
    }
}

extern "C" void kernel_launch(void* const* d_in, const int* in_sizes, int n_in,
                              void* d_out, int out_size, void* d_ws, size_t ws_size,
                              hipStream_t stream) {
    const float* preds = (const float*)d_in[0];
    const float* targets = (const float*)d_in[1];
    float* out = (float*)d_out;

    const int total = in_sizes[0];                 // N*S*S*D
    const int n_cells = total / DDIM;              // N*S*S
    const int N = total / (SGRID * SGRID * DDIM);  // 16384

    float* partials = (float*)d_ws;                 // [0, MAIN_BLOCKS)
    float* probe_sink = (float*)d_ws + MAIN_BLOCKS; // [MAIN_BLOCKS, +PROBE_BLOCKS)

    yolo_loss_main<<<MAIN_BLOCKS, 64, 0, stream>>>(preds, targets, partials,
                                                   n_cells);
    yolo_loss_reduce<<<1, RTHREADS, 0, stream>>>(partials, MAIN_BLOCKS,
                                                 1.0f / (float)N, out);
    probe_read<<<PROBE_BLOCKS, PROBE_THREADS, 0, stream>>>((const float4*)preds,
                                                           probe_sink);
}